// Round 6
// baseline (2572.454 us; speedup 1.0000x reference)
//
#include <hip/hip_runtime.h>
#include <hip/hip_bf16.h>
#include <cstdint>

#define D_DIM 2048
#define F_DIM 1024
#define E_NUM 64
#define K_TOP 8
#define CAP   1024
#define BKB   256      // big K tile staged in LDS (8 subtiles of 32)

typedef __attribute__((ext_vector_type(8))) short short8;
typedef __attribute__((ext_vector_type(4))) float f32x4;

__device__ __forceinline__ uint16_t f_to_bf16(float f) {
    union { float f; uint32_t u; } v; v.f = f;
    uint32_t r = v.u + 0x7FFF + ((v.u >> 16) & 1);
    return (uint16_t)(r >> 16);
}
__device__ __forceinline__ uint32_t pack2(float a, float b) {
    __hip_bfloat162 t = __float22bfloat162_rn(make_float2(a, b));
    return *reinterpret_cast<uint32_t*>(&t);
}
__device__ __forceinline__ short8 pack_frag(const float* v) {
    union { short8 s; uint32_t u[4]; } r;
    r.u[0] = pack2(v[0], v[1]); r.u[1] = pack2(v[2], v[3]);
    r.u[2] = pack2(v[4], v[5]); r.u[3] = pack2(v[6], v[7]);
    return r.s;
}

// ---------------- x -> bf16 ----------------
__global__ __launch_bounds__(256) void cvtx_k(const float* __restrict__ x,
        uint16_t* __restrict__ xb, int n8) {
    int i = blockIdx.x * 256 + threadIdx.x;
    if (i >= n8) return;
    const float4* p = (const float4*)x + (size_t)i * 2;
    float4 a = p[0], b = p[1];
    uint4 o;
    o.x = pack2(a.x, a.y); o.y = pack2(a.z, a.w);
    o.z = pack2(b.x, b.y); o.w = pack2(b.z, b.w);
    ((uint4*)xb)[i] = o;
}

// ---------------- Router ----------------
__global__ __launch_bounds__(64) void router_k(const float* __restrict__ x,
        const float* __restrict__ gw, int* __restrict__ topi,
        float* __restrict__ topw) {
    int t = blockIdx.x;
    int tid = threadIdx.x;
    __shared__ float xs[D_DIM];
    __shared__ float lgs[E_NUM];
    const float* xr = x + (size_t)t * D_DIM;
    for (int d = tid; d < D_DIM; d += 64) xs[d] = xr[d];
    __syncthreads();
    const float* w = gw + (size_t)tid * D_DIM;
    float acc = 0.f;
    #pragma unroll 8
    for (int d = 0; d < D_DIM; ++d) acc = fmaf(xs[d], w[d], acc);
    lgs[tid] = acc;
    __syncthreads();
    if (tid == 0) {
        float mx = -INFINITY;
        for (int e = 0; e < E_NUM; ++e) mx = fmaxf(mx, lgs[e]);
        float se = 0.f;
        for (int e = 0; e < E_NUM; ++e) se += expf(lgs[e] - mx);
        float inv = 1.f / se;
        uint64_t used = 0;
        for (int k = 0; k < K_TOP; ++k) {
            int bi = 0; float bv = -INFINITY;
            for (int e = 0; e < E_NUM; ++e) {
                if (!((used >> e) & 1) && lgs[e] > bv) { bv = lgs[e]; bi = e; }
            }
            used |= 1ull << bi;
            topi[t * K_TOP + k] = bi;
            topw[t * K_TOP + k] = expf(bv - mx) * inv;
        }
    }
}

// ---------------- Slot assignment ----------------
__global__ void assign_k(const int* __restrict__ topi, const float* __restrict__ topw,
        int* __restrict__ cnt, int* __restrict__ rowtok, float* __restrict__ aw, int T) {
    int t = blockIdx.x * blockDim.x + threadIdx.x;
    if (t >= T) return;
    for (int k = 0; k < K_TOP; ++k) {
        int e = topi[t * K_TOP + k];
        int pos = atomicAdd(&cnt[e], 1);
        if (pos < CAP) {
            rowtok[e * CAP + pos] = t;
            aw[e * CAP + pos] = topw[t * K_TOP + k];
        }
    }
}

// ======== Gate+Up: 128m x 128f, A in LDS (BKB=256), B frag-direct fp32 ========
// 8 waves span the f-dim (wave tile 128m x 16f) -> each B byte loaded once.
__global__ __launch_bounds__(512) void gateup_k(const uint16_t* __restrict__ xb,
        const float* __restrict__ wg, const float* __restrict__ wu,
        const int* __restrict__ cnt, const int* __restrict__ rowtok,
        uint16_t* __restrict__ h) {
    int flat = blockIdx.x;
    int xcd = flat & 7;
    int idx = flat >> 3;
    int m = idx & 7;
    int sloc = idx >> 3;              // 0..63
    int strip = sloc * 8 + xcd;       // 0..511 = e*8 + f  (512%8==0, bijective)
    int e = strip >> 3;
    int f = strip & 7;
    int m0 = m * 128;
    int ne = min(cnt[e], CAP);
    int nr = ne - m0;
    if (nr <= 0) return;
    if (nr > 128) nr = 128;
    int slot0 = e * CAP + m0;
    int fbase = f * 128;

    __shared__ __align__(16) unsigned char L[8][128][72];   // 73728 B

    int tid = threadIdx.x;
    int l = tid & 63, wid = tid >> 6;
    int ln = l & 15, lq = l >> 4;

    // A staging: row = tid/4, chunk = tid%4 (16B each); 8 subtiles per big tile
    int arow = tid >> 2, achk = tid & 3;
    int tok = rowtok[slot0 + min(arow, nr - 1)];
    const uint16_t* agp = xb + (size_t)tok * D_DIM + achk * 8;
    // B lane base: col = fbase + wid*16 + ln, k-oct = lq*8
    size_t wboff = (size_t)e * ((size_t)D_DIM * F_DIM) + (size_t)(lq * 8) * F_DIM
                 + (size_t)(fbase + wid * 16 + ln);
    const float* gp = wg + wboff;
    const float* up = wu + wboff;

    f32x4 accg[8], accu[8];
    #pragma unroll
    for (int mi = 0; mi < 8; ++mi) {
        accg[mi] = (f32x4){0.f, 0.f, 0.f, 0.f};
        accu[mi] = (f32x4){0.f, 0.f, 0.f, 0.f};
    }

    uint4 apre[8];
    #pragma unroll
    for (int s = 0; s < 8; ++s) apre[s] = *(const uint4*)(agp + s * 32);
    #pragma unroll
    for (int s = 0; s < 8; ++s) *(uint4*)(&L[s][arow][achk * 16]) = apre[s];
    __syncthreads();

    const int NBT = D_DIM / BKB;      // 8
    for (int bt = 0; bt < NBT; ++bt) {
        if (bt + 1 < NBT) {
            #pragma unroll
            for (int s = 0; s < 8; ++s)
                apre[s] = *(const uint4*)(agp + (bt + 1) * BKB + s * 32);
        }
        size_t kbase = (size_t)bt * BKB * F_DIM;
        float gv[2][8], uv[2][8];
        #pragma unroll
        for (int j = 0; j < 8; ++j) {
            gv[0][j] = gp[kbase + (size_t)j * F_DIM];
            uv[0][j] = up[kbase + (size_t)j * F_DIM];
        }
        #pragma unroll
        for (int s = 0; s < 8; ++s) {
            const int cur = s & 1, nxt = (s & 1) ^ 1;
            if (s + 1 < 8) {
                size_t kb2 = kbase + (size_t)((s + 1) * 32) * F_DIM;
                #pragma unroll
                for (int j = 0; j < 8; ++j) {
                    gv[nxt][j] = gp[kb2 + (size_t)j * F_DIM];
                    uv[nxt][j] = up[kb2 + (size_t)j * F_DIM];
                }
            }
            short8 bgf = pack_frag(gv[cur]);
            short8 buf_ = pack_frag(uv[cur]);
            #pragma unroll
            for (int mi = 0; mi < 8; ++mi) {
                short8 af = *(const short8*)(&L[s][mi * 16 + ln][lq * 16]);
                accg[mi] = __builtin_amdgcn_mfma_f32_16x16x32_bf16(af, bgf,  accg[mi], 0, 0, 0);
                accu[mi] = __builtin_amdgcn_mfma_f32_16x16x32_bf16(af, buf_, accu[mi], 0, 0, 0);
            }
        }
        __syncthreads();
        if (bt + 1 < NBT) {
            #pragma unroll
            for (int s = 0; s < 8; ++s) *(uint4*)(&L[s][arow][achk * 16]) = apre[s];
        }
        __syncthreads();
    }

    // epilogue: h = silu(g)*u
    #pragma unroll
    for (int mi = 0; mi < 8; ++mi) {
        int rb = mi * 16 + lq * 4;
        #pragma unroll
        for (int j = 0; j < 4; ++j) {
            int row = rb + j;
            if (row < nr) {
                float g = accg[mi][j], u = accu[mi][j];
                float hv = g / (1.f + __expf(-g)) * u;
                h[(size_t)(slot0 + row) * F_DIM + fbase + wid * 16 + ln] = f_to_bf16(hv);
            }
        }
    }
}

// ======== Down: 128m x 256d, A(h) in LDS (BKB=256), B frag-direct fp32 ========
// wave tile 128m x 32d (2 ntiles per wave)
__global__ __launch_bounds__(512) void down_k(const uint16_t* __restrict__ h,
        const float* __restrict__ wd, const int* __restrict__ cnt,
        const int* __restrict__ rowtok, const float* __restrict__ aw,
        float* __restrict__ out) {
    int flat = blockIdx.x;
    int xcd = flat & 7;
    int idx = flat >> 3;
    int m = idx & 7;
    int sloc = idx >> 3;              // 0..63
    int strip = sloc * 8 + xcd;       // 0..511 = e*8 + dt
    int e = strip >> 3;
    int dt = strip & 7;
    int m0 = m * 128;
    int ne = min(cnt[e], CAP);
    int nr = ne - m0;
    if (nr <= 0) return;
    if (nr > 128) nr = 128;
    int slot0 = e * CAP + m0;
    int dbase = dt * 256;

    __shared__ __align__(16) unsigned char L[8][128][72];

    int tid = threadIdx.x;
    int l = tid & 63, wid = tid >> 6;
    int ln = l & 15, lq = l >> 4;

    int arow = tid >> 2, achk = tid & 3;
    const uint16_t* agp = h + (size_t)(slot0 + min(arow, nr - 1)) * F_DIM + achk * 8;
    size_t wboff = (size_t)e * ((size_t)F_DIM * D_DIM) + (size_t)(lq * 8) * D_DIM
                 + (size_t)(dbase + wid * 32 + ln);
    const float* bp = wd + wboff;

    f32x4 acc[8][2];
    #pragma unroll
    for (int mi = 0; mi < 8; ++mi)
        #pragma unroll
        for (int nj = 0; nj < 2; ++nj)
            acc[mi][nj] = (f32x4){0.f, 0.f, 0.f, 0.f};

    uint4 apre[8];
    #pragma unroll
    for (int s = 0; s < 8; ++s) apre[s] = *(const uint4*)(agp + s * 32);
    #pragma unroll
    for (int s = 0; s < 8; ++s) *(uint4*)(&L[s][arow][achk * 16]) = apre[s];
    __syncthreads();

    const int NBT = F_DIM / BKB;      // 4
    for (int bt = 0; bt < NBT; ++bt) {
        if (bt + 1 < NBT) {
            #pragma unroll
            for (int s = 0; s < 8; ++s)
                apre[s] = *(const uint4*)(agp + (bt + 1) * BKB + s * 32);
        }
        size_t kbase = (size_t)bt * BKB * D_DIM;
        float bv[2][2][8];            // [buf][ntile][j]
        #pragma unroll
        for (int nj = 0; nj < 2; ++nj)
            #pragma unroll
            for (int j = 0; j < 8; ++j)
                bv[0][nj][j] = bp[kbase + (size_t)j * D_DIM + nj * 16];
        #pragma unroll
        for (int s = 0; s < 8; ++s) {
            const int cur = s & 1, nxt = (s & 1) ^ 1;
            if (s + 1 < 8) {
                size_t kb2 = kbase + (size_t)((s + 1) * 32) * D_DIM;
                #pragma unroll
                for (int nj = 0; nj < 2; ++nj)
                    #pragma unroll
                    for (int j = 0; j < 8; ++j)
                        bv[nxt][nj][j] = bp[kb2 + (size_t)j * D_DIM + nj * 16];
            }
            short8 bf0 = pack_frag(bv[cur][0]);
            short8 bf1 = pack_frag(bv[cur][1]);
            #pragma unroll
            for (int mi = 0; mi < 8; ++mi) {
                short8 af = *(const short8*)(&L[s][mi * 16 + ln][lq * 16]);
                acc[mi][0] = __builtin_amdgcn_mfma_f32_16x16x32_bf16(af, bf0, acc[mi][0], 0, 0, 0);
                acc[mi][1] = __builtin_amdgcn_mfma_f32_16x16x32_bf16(af, bf1, acc[mi][1], 0, 0, 0);
            }
        }
        __syncthreads();
        if (bt + 1 < NBT) {
            #pragma unroll
            for (int s = 0; s < 8; ++s) *(uint4*)(&L[s][arow][achk * 16]) = apre[s];
        }
        __syncthreads();
    }

    #pragma unroll
    for (int mi = 0; mi < 8; ++mi) {
        int rb = mi * 16 + lq * 4;
        #pragma unroll
        for (int j = 0; j < 4; ++j) {
            int row = rb + j;
            if (row < nr) {
                int slot = slot0 + row;
                int tok = rowtok[slot];
                float wgt = aw[slot];
                float* orow = out + (size_t)tok * D_DIM + dbase + wid * 32 + ln;
                atomicAdd(&orow[0],  acc[mi][0][j] * wgt);
                atomicAdd(&orow[16], acc[mi][1][j] * wgt);
            }
        }
    }
}

extern "C" void kernel_launch(void* const* d_in, const int* in_sizes, int n_in,
                              void* d_out, int out_size, void* d_ws, size_t ws_size,
                              hipStream_t stream) {
    const float* x  = (const float*)d_in[0];
    const float* gw = (const float*)d_in[1];
    const float* wg = (const float*)d_in[2];
    const float* wu = (const float*)d_in[3];
    const float* wd = (const float*)d_in[4];
    float* out = (float*)d_out;
    int T = in_sizes[0] / D_DIM;

    char* ws = (char*)d_ws;
    size_t off = 0;
    auto alloc = [&](size_t bytes) -> void* {
        void* p = ws + off;
        off = (off + bytes + 255) & ~(size_t)255;
        return p;
    };
    int*      cnt    = (int*)     alloc(E_NUM * sizeof(int));
    int*      topi   = (int*)     alloc((size_t)T * K_TOP * sizeof(int));
    float*    topw   = (float*)   alloc((size_t)T * K_TOP * sizeof(float));
    int*      rowtok = (int*)     alloc((size_t)E_NUM * CAP * sizeof(int));
    float*    aw     = (float*)   alloc((size_t)E_NUM * CAP * sizeof(float));
    uint16_t* xb     = (uint16_t*)alloc((size_t)T * D_DIM * sizeof(uint16_t));
    uint16_t* h      = (uint16_t*)alloc((size_t)E_NUM * CAP * F_DIM * sizeof(uint16_t));

    hipMemsetAsync(cnt, 0, E_NUM * sizeof(int), stream);
    hipMemsetAsync(out, 0, (size_t)out_size * sizeof(float), stream);

    int n8 = T * D_DIM / 8;
    cvtx_k<<<(n8 + 255) / 256, 256, 0, stream>>>(x, xb, n8);
    router_k<<<T, 64, 0, stream>>>(x, gw, topi, topw);
    assign_k<<<(T + 255) / 256, 256, 0, stream>>>(topi, topw, cnt, rowtok, aw, T);
    gateup_k<<<E_NUM * 8 * 8, 512, 0, stream>>>(xb, wg, wu, cnt, rowtok, h);
    down_k<<<E_NUM * 8 * 8, 512, 0, stream>>>(h, wd, cnt, rowtok, aw, out);
}